// Round 9
// baseline (3472.626 us; speedup 1.0000x reference)
//
#include <hip/hip_runtime.h>
#include <math.h>

// GRANCascadingPredictor — round 9: double-buffered LDS (1 barrier/iter) +
// 64x128 wave tile (128x256 block).
//
// R8 counters: RZ GEMM MfmaUtil 16%, over-fetch gone (39MB), HBM 11%.
// Cycle model per block-iter (1612 cy): MFMA 258 + LDS ~500 + ~600 exposed
// global latency at the 2 barriers (prefetch window too short). Fixes:
//  * dbuf LDS: compute buf[k&1], prefetch k+1 to regs, stage to buf[~],
//    ONE barrier -> latency window = full iter.
//  * wave tile 64x128 (acc 4x8, ~230 VGPR, launch_bounds(256,2)), block
//    128x256, LDS 60KB, 2 blocks/CU; FLOP/LDS-byte 21 -> 28.
// ws unchanged: 178.6MB < 189.18MB proven.

#define Bn 16384
#define Hn 512
#define Dn 256
#define Tn 768

#define EPI_NONE 0
#define EPI_RELU 1
#define EPI_SIG 2
#define EPI_SIGMUL 3
#define EPI_RELUGATHER 4
#define EPI_GRU 5

typedef unsigned short bfu;
typedef _Float16 f16;
typedef f16 h4 __attribute__((ext_vector_type(4)));
typedef f16 half8 __attribute__((ext_vector_type(8)));
typedef float floatx4 __attribute__((ext_vector_type(4)));

// fp16 weight arena offsets (halves)
#define HTEXTW 0
#define HPROJW 196608
#define HHW1 327680
#define HWE1 589824
#define HMSGW2 1376256
#define HATTW2 1900544
#define HWIH 2162688
#define HWHH 3735552
#define HTOTAL 5308416
// fp32 bias arena offsets (floats)
#define FTEXTB 0
#define FPROJB 256
#define FHB1 768
#define FGBIH 1280
#define FGBHH 4352
#define FBGRZ 7424
#define FBE1 9472
#define FBE2 14080

__device__ __forceinline__ float sigf(float x) { return 1.f / (1.f + expf(-x)); }

__device__ __forceinline__ float b2f(bfu v) {
  union { unsigned q; float f; } c;
  c.q = (unsigned)v << 16;
  return c.f;
}
__device__ __forceinline__ float4 bf4(uint2 u) {
  union { unsigned q; float f; } c;
  float4 r;
  c.q = u.x << 16;          r.x = c.f;
  c.q = u.x & 0xFFFF0000u;  r.y = c.f;
  c.q = u.y << 16;          r.z = c.f;
  c.q = u.y & 0xFFFF0000u;  r.w = c.f;
  return r;
}
__device__ __forceinline__ unsigned f2bu(float x) {
  union { float f; unsigned u; } c;
  c.f = x;
  return (c.u + 0x7FFFu + ((c.u >> 16) & 1u)) >> 16;
}
__device__ __forceinline__ float4 h2f4(h4 h) {
  return make_float4((float)h.x, (float)h.y, (float)h.z, (float)h.w);
}
__device__ __forceinline__ h4 f2h4c(float4 v) {
  h4 r;
  r.x = (f16)v.x; r.y = (f16)v.y; r.z = (f16)v.z; r.w = (f16)v.w;
  return r;
}
__device__ __forceinline__ half8 ff2h8(float4 a, float4 b) {
  half8 r;
  r[0] = (f16)a.x; r[1] = (f16)a.y; r[2] = (f16)a.z; r[3] = (f16)a.w;
  r[4] = (f16)b.x; r[5] = (f16)b.y; r[6] = (f16)b.z; r[7] = (f16)b.w;
  return r;
}
__device__ __forceinline__ half8 bf2h8(uint4 u) {
  uint2 lo; lo.x = u.x; lo.y = u.y;
  uint2 hi; hi.x = u.z; hi.y = u.w;
  return ff2h8(bf4(lo), bf4(hi));
}

__global__ void detect_k(const unsigned* __restrict__ p, int* __restrict__ flag) {
  __shared__ float red[256];
  const int t = threadIdx.x;
  union { unsigned q; float f; } c;
  c.q = p[t] << 16;
  float m = fabsf(c.f);
  if (!(m == m)) m = 1e30f;
  red[t] = m;
  __syncthreads();
  for (int s = 128; s > 0; s >>= 1) {
    if (t < s) red[t] = fmaxf(red[t], red[t + s]);
    __syncthreads();
  }
  if (t == 0) flag[0] = (red[0] < 1e3f) ? 1 : 0;
}

__device__ __forceinline__ float cvld(const void* p, size_t i, int fl) {
  return fl ? b2f(((const bfu*)p)[i]) : ((const float*)p)[i];
}

__global__ void convF_k(const void* __restrict__ src, size_t off, float* __restrict__ dst,
                        int n, const int* __restrict__ flagp) {
  const int i = blockIdx.x * 256 + threadIdx.x;
  if (i < n) dst[i] = cvld(src, off + i, flagp[0]);
}
__global__ void convH_k(const void* __restrict__ src, size_t off, f16* __restrict__ dst,
                        int n, const int* __restrict__ flagp) {
  const int i = blockIdx.x * 256 + threadIdx.x;
  if (i < n) dst[i] = (f16)cvld(src, off + i, flagp[0]);
}
__global__ void convT_k(const void* __restrict__ src, size_t off, f16* __restrict__ dst,
                        int K, int N, const int* __restrict__ flagp) {
  __shared__ f16 tile[32][33];
  const int t = threadIdx.x;
  const int c = t & 31, r0 = t >> 5;
  const int kb = blockIdx.y * 32, nb = blockIdx.x * 32;
  const int fl = flagp[0];
#pragma unroll
  for (int i = 0; i < 4; ++i)
    tile[r0 + i * 8][c] = (f16)cvld(src, off + (size_t)(kb + r0 + i * 8) * N + nb + c, fl);
  __syncthreads();
#pragma unroll
  for (int i = 0; i < 4; ++i)
    dst[(size_t)(nb + r0 + i * 8) * K + kb + c] = tile[c][r0 + i * 8];
}
__global__ void addv_k(const float* __restrict__ a, const float* __restrict__ b,
                       float* __restrict__ o, int n) {
  const int i = blockIdx.x * 256 + threadIdx.x;
  if (i < n) o[i] = a[i] + b[i];
}
__global__ void btype_k(const void* __restrict__ b, size_t bOff,
                        const void* __restrict__ wr, size_t wrOff,
                        float* __restrict__ dst, int N, int dstStride,
                        const int* __restrict__ flagp) {
  const int i = blockIdx.x * 256 + threadIdx.x;
  const int fl = flagp[0];
  if (i < 3 * N) {
    const int t = i / N, n = i % N;
    dst[(size_t)t * dstStride + n] = cvld(b, bOff + n, fl) + cvld(wr, wrOff + i, fl);
  }
}
__global__ void gather_k(const int* __restrict__ ids, const void* __restrict__ emb,
                         f16* __restrict__ Xc, const int* __restrict__ flagp) {
  const int r = blockIdx.x, t = threadIdx.x;
  const int id = ids[r];
  float4 v;
  if (flagp[0])
    v = bf4(((const uint2*)((const bfu*)emb + (size_t)id * Dn))[t]);
  else
    v = ((const float4*)((const float*)emb + (size_t)id * Dn))[t];
  ((h4*)(Xc + (size_t)r * Dn))[t] = f2h4c(v);
}

// C[M,N] = epi(A @ W + bias), MFMA 16x16x32, 128x256 block, 4 waves 2x2,
// wave tile 64x128, double-buffered LDS, one barrier per k-iter.
// 1D grid = nCols*nRows (nRows%8==0), XCD-swizzled: xcd=bid&7 owns row band.
// AM: 1=A flag-dtyped global rows rowOff+row; 2=A row e=rowOff+row ->
//     state[src(e)]-state[e+Bn] (fp16, stride 512); 5=A fp16 (aStride);
//     6=A=[P fp16 | state fp16], k<512->Ap else Ap2 (both stride 512).
// BM: 0=Wt[N][K]; 1=k<512->Wt[n][k] else Wt2[n][k-512] (stride 512).
// CT: 0=C fp32; 2=C fp16. BTY: bias += ((rowOff+row0)>>14)*768.
// EPI_GRU: r,z=ex1[row*1024+{col,512+col}], hn=ex2[row*512+col], C=state fp16
//          in-place: s=(float)C; C=(1-z)*tanh(x+r*hn)+z*s.
template <int EPI, int AM, int BM, int CT, int BTY>
__global__ __launch_bounds__(256, 2) void hgemm_k(
    const void* __restrict__ Ap, const void* __restrict__ Ap2,
    const f16* __restrict__ Wt, const f16* __restrict__ Wt2,
    const float* __restrict__ bias,
    const f16* __restrict__ ex1, const f16* __restrict__ ex2,
    const int* __restrict__ gidx, const void* __restrict__ gtab,
    void* __restrict__ C, int N, int K, int aStride, int rowOff, int nRows,
    const int* __restrict__ flagp) {
  __shared__ __align__(16) f16 As[2][128][40];
  __shared__ __align__(16) f16 Bs[2][256][40];
  const int t = threadIdx.x;
  const int bid = blockIdx.x;
  const int rowsPerX = nRows >> 3;
  const int slot = bid >> 3;
  const int row0 = ((bid & 7) * rowsPerX + slot % rowsPerX) * 128;
  const int col0 = (slot / rowsPerX) * 256;
  const int lane = t & 63;
  const int wv = t >> 6;
  const int wm = wv >> 1, wn = wv & 1;
  const int l16 = lane & 15, quad = lane >> 4;
  const int arow = t & 127;
  const int ak0 = (t >> 7) * 16;  // this thread stages k-groups ak0, ak0+8
  const int fl = (AM == 1 || EPI == EPI_RELUGATHER) ? flagp[0] : 0;

  floatx4 acc[4][8];
#pragma unroll
  for (int mi = 0; mi < 4; ++mi)
#pragma unroll
    for (int ni = 0; ni < 8; ++ni) acc[mi][ni] = (floatx4){0.f, 0.f, 0.f, 0.f};

  auto fetchA = [&](int k) -> half8 {  // k absolute
    const int m = row0 + arow;
    if (AM == 5) {
      return *(const half8*)((const f16*)Ap + (size_t)m * aStride + k);
    } else if (AM == 1) {
      const size_t o = (size_t)(rowOff + m) * aStride + k;
      if (fl) return bf2h8(*(const uint4*)((const bfu*)Ap + o));
      const float* ap = (const float*)Ap + o;
      return ff2h8(*(const float4*)ap, *(const float4*)(ap + 4));
    } else if (AM == 6) {
      if (k < 512) return *(const half8*)((const f16*)Ap + (size_t)m * 512 + k);
      return *(const half8*)((const f16*)Ap2 + (size_t)m * 512 + (k - 512));
    } else {  // AM == 2: state-diff rows, state fp16
      const int e = rowOff + m;
      const int s = (e < 2 * Bn) ? e : e - Bn;
      const f16* st = (const f16*)Ap;
      half8 x = *(const half8*)(st + (size_t)s * 512 + k);
      half8 y = *(const half8*)(st + (size_t)(e + Bn) * 512 + k);
      return x - y;
    }
  };
  auto fetchB = [&](int brow, int k) -> half8 {
    const int n = col0 + brow;
    if (BM == 0) return *(const half8*)(Wt + (size_t)n * K + k);
    if (k < 512) return *(const half8*)(Wt + (size_t)n * 512 + k);
    return *(const half8*)(Wt2 + (size_t)n * 512 + k - 512);
  };

  half8 pa0, pa1, pb0, pb1, pb2, pb3;
  auto prefetch = [&](int kk) {
    pa0 = fetchA(kk + ak0);
    pa1 = fetchA(kk + ak0 + 8);
    pb0 = fetchB(arow, kk + ak0);
    pb1 = fetchB(arow, kk + ak0 + 8);
    pb2 = fetchB(arow + 128, kk + ak0);
    pb3 = fetchB(arow + 128, kk + ak0 + 8);
  };
  auto stage = [&](int buf) {
    *(half8*)&As[buf][arow][ak0] = pa0;
    *(half8*)&As[buf][arow][ak0 + 8] = pa1;
    *(half8*)&Bs[buf][arow][ak0] = pb0;
    *(half8*)&Bs[buf][arow][ak0 + 8] = pb1;
    *(half8*)&Bs[buf][arow + 128][ak0] = pb2;
    *(half8*)&Bs[buf][arow + 128][ak0 + 8] = pb3;
  };

  prefetch(0);
  stage(0);
  __syncthreads();
  const int nk = K >> 5;
  for (int kt = 0; kt < nk; ++kt) {
    const int cur = kt & 1;
    if (kt + 1 < nk) prefetch((kt + 1) * 32);
    half8 a8[4], b8[8];
#pragma unroll
    for (int mi = 0; mi < 4; ++mi)
      a8[mi] = *(const half8*)&As[cur][wm * 64 + mi * 16 + l16][quad * 8];
#pragma unroll
    for (int ni = 0; ni < 8; ++ni)
      b8[ni] = *(const half8*)&Bs[cur][wn * 128 + ni * 16 + l16][quad * 8];
#pragma unroll
    for (int mi = 0; mi < 4; ++mi)
#pragma unroll
      for (int ni = 0; ni < 8; ++ni)
        acc[mi][ni] = __builtin_amdgcn_mfma_f32_16x16x32_f16(a8[mi], b8[ni],
                                                             acc[mi][ni], 0, 0, 0);
    if (kt + 1 < nk) stage(cur ^ 1);
    __syncthreads();
  }

  const float* bp = bias;
  if (BTY) bp = bias + ((rowOff + row0) >> 14) * 768;
  const int colBase = col0 + wn * 128;
  const int rowBase = row0 + wm * 64;
#pragma unroll
  for (int mi = 0; mi < 4; ++mi) {
    const int r0r = rowBase + mi * 16 + quad * 4;
#pragma unroll
    for (int ni = 0; ni < 8; ++ni) {
      const int col = colBase + ni * 16 + l16;
      const float bb = bp[col];
      floatx4 v = acc[mi][ni];
#pragma unroll
      for (int rg = 0; rg < 4; ++rg) {
        const int row = r0r + rg;
        float x = v[rg] + bb;
        if (EPI == EPI_RELU || EPI == EPI_RELUGATHER) x = fmaxf(x, 0.f);
        if (EPI == EPI_SIG) x = sigf(x);
        if (EPI == EPI_SIGMUL)
          x = sigf(x) * (float)ex1[(size_t)row * N + col];
        if (EPI == EPI_RELUGATHER) {
          const int grow = gidx[rowOff + row];
          x += fl ? b2f(((const bfu*)gtab)[(size_t)grow * N + col])
                  : ((const float*)gtab)[(size_t)grow * N + col];
        }
        if (EPI == EPI_GRU) {
          const float r_ = (float)ex1[(size_t)row * 1024 + col];
          const float z_ = (float)ex1[(size_t)row * 1024 + 512 + col];
          const float hn = (float)ex2[(size_t)row * 512 + col];
          f16* cf = (f16*)C + (size_t)row * 512 + col;
          const float s = (float)*cf;
          const float n_ = tanhf(x + r_ * hn);
          *cf = (f16)((1.f - z_) * n_ + z_ * s);
        } else if (CT == 0) {
          ((float*)C)[(size_t)row * N + col] = x;
        } else {
          ((f16*)C)[(size_t)row * N + col] = (f16)x;
        }
      }
    }
  }
}

// r=0 (A nodes, agg==0): i_n = bih_n; state fp16 updated in place.
__global__ void gate0_k(const f16* __restrict__ RZ, const f16* __restrict__ HN,
                        const float* __restrict__ bihn, f16* __restrict__ st) {
  const int idx = blockIdx.x * blockDim.x + threadIdx.x;
  const int m = idx >> 7;
  const int c = (idx & 127) << 2;
  float4 r4 = h2f4(*(const h4*)(RZ + (size_t)m * 1024 + c));
  float4 z4 = h2f4(*(const h4*)(RZ + (size_t)m * 1024 + 512 + c));
  float4 hn = h2f4(*(const h4*)(HN + (size_t)m * 512 + c));
  float4 b4 = *(const float4*)(bihn + c);
  f16* sp = st + (size_t)m * 512 + c;
  float4 s = h2f4(*(const h4*)sp);
  float4 o;
  float n_;
  n_ = tanhf(b4.x + r4.x * hn.x); o.x = (1.f - z4.x) * n_ + z4.x * s.x;
  n_ = tanhf(b4.y + r4.y * hn.y); o.y = (1.f - z4.y) * n_ + z4.y * s.y;
  n_ = tanhf(b4.z + r4.z * hn.z); o.z = (1.f - z4.z) * n_ + z4.z * s.z;
  n_ = tanhf(b4.w + r4.w * hn.w); o.w = (1.f - z4.w) * n_ + z4.w * s.w;
  *(h4*)sp = f2h4c(o);
}

__global__ void hdiff_k(const f16* __restrict__ st, f16* __restrict__ Dh) {
  const int m = blockIdx.x, t = threadIdx.x;  // 64 thr x half8
  half8 a = ((const half8*)(st + (size_t)m * Hn))[t];
  half8 b = ((const half8*)(st + (size_t)(2 * Bn + m) * Hn))[t];
  ((half8*)(Dh + (size_t)m * Hn))[t] = a - b;
}

// packed-fp16 relu (sign-bit mask)
__global__ void relu_h_k(uint4* __restrict__ p, long n) {
  long i = (long)blockIdx.x * blockDim.x + threadIdx.x;
  if (i < n) {
    uint4 v = p[i];
    v.x = ((v.x & 0x8000u) ? 0u : (v.x & 0xFFFFu)) |
          ((v.x & 0x80000000u) ? 0u : (v.x & 0xFFFF0000u));
    v.y = ((v.y & 0x8000u) ? 0u : (v.y & 0xFFFFu)) |
          ((v.y & 0x80000000u) ? 0u : (v.y & 0xFFFF0000u));
    v.z = ((v.z & 0x8000u) ? 0u : (v.z & 0xFFFFu)) |
          ((v.z & 0x80000000u) ? 0u : (v.z & 0xFFFF0000u));
    v.w = ((v.w & 0x8000u) ? 0u : (v.w & 0xFFFFu)) |
          ((v.w & 0x80000000u) ? 0u : (v.w & 0xFFFF0000u));
    p[i] = v;
  }
}

__global__ void head2_k(const f16* __restrict__ Hh, const void* __restrict__ W2,
                        const void* __restrict__ b2, void* __restrict__ out,
                        const int* __restrict__ flagp) {
  __shared__ __align__(16) float Ws[64][32];
  __shared__ __align__(16) float As2[8][64];
  const int t = threadIdx.x;
  const int r0 = blockIdx.x * 8;
  const int lr = t >> 5, c = t & 31;
  const int fl = flagp[0];
  float acc = 0.f;
  for (int kc = 0; kc < 512; kc += 64) {
    __syncthreads();
    if (fl) {
      uint4 u = ((const uint4*)((const bfu*)W2 + (size_t)kc * 32))[t];
      uint2 lo; lo.x = u.x; lo.y = u.y;
      uint2 hi; hi.x = u.z; hi.y = u.w;
      ((float4*)&Ws[0][0])[t * 2] = bf4(lo);
      ((float4*)&Ws[0][0])[t * 2 + 1] = bf4(hi);
    } else {
      const float4* src = (const float4*)((const float*)W2 + (size_t)kc * 32);
      ((float4*)&Ws[0][0])[t * 2] = src[t * 2];
      ((float4*)&Ws[0][0])[t * 2 + 1] = src[t * 2 + 1];
    }
    {
      const int i = t * 2, rr = i >> 6, cc = i & 63;
      const f16* hp = Hh + (size_t)(r0 + rr) * 512 + kc + cc;
      As2[rr][cc] = (float)hp[0];
      As2[rr][cc + 1] = (float)hp[1];
    }
    __syncthreads();
#pragma unroll
    for (int k = 0; k < 64; ++k) acc = fmaf(As2[lr][k], Ws[k][c], acc);
  }
  const float bb = fl ? b2f(((const bfu*)b2)[c]) : ((const float*)b2)[c];
  const float r = acc + bb;
  const size_t o = (size_t)(r0 + lr) * 32 + c;
  if (fl) ((bfu*)out)[o] = (bfu)f2bu(r);
  else ((float*)out)[o] = r;
}

extern "C" void kernel_launch(void* const* d_in, const int* in_sizes, int n_in,
                              void* d_out, int out_size, void* d_ws, size_t ws_size,
                              hipStream_t stream) {
  const int* a_ids = (const int*)d_in[0];
  const int* event_ids = (const int*)d_in[1];
  const int* b_ids = (const int*)d_in[2];
  const int* c_ids = (const int*)d_in[3];
  const void* text_ab = d_in[4];
  const void* ent_emb = d_in[5];

  char* w = (char*)d_ws;
  int* flag = (int*)w;   w += 256;
  float* bf = (float*)w; w += 65536;
  f16* hw = (f16*)w;     w += (size_t)HTOTAL * 2;       // 10.6 MB
  f16* P = (f16*)w;      w += (size_t)3 * Bn * 512 * 2; // 48 MB
  f16* S = (f16*)w;      w += (size_t)50331648;         // 48 MB scratch
  f16* state = (f16*)w;                                 // 64 MB
  f16* RZ = S;                          // Bn x 1024 (32 MB)
  f16* HN = S + (size_t)Bn * 1024;      // Bn x 512  (16 MB)
  const dim3 blk(256);

  detect_k<<<dim3(1), blk, 0, stream>>>((const unsigned*)ent_emb, flag);

  struct CF { int idx; size_t off; int dst; int n; };
  const CF cfs[9] = {{7, 0, FTEXTB, 256},   {9, 0, FPROJB, 512},
                     {23, 0, FHB1, 512},    {20, 0, FGBIH, 3072},
                     {21, 0, FGBHH, 3072},  {13, 0, FBE2, 512},
                     {17, 0, FBE2 + 512, 512}, {13, 512, FBE2 + 1024, 512},
                     {17, 512, FBE2 + 1536, 512}};
  for (int i = 0; i < 9; ++i)
    convF_k<<<dim3((cfs[i].n + 255) / 256), blk, 0, stream>>>(
        d_in[cfs[i].idx], cfs[i].off, bf + cfs[i].dst, cfs[i].n, flag);

  convT_k<<<dim3(8, 24), blk, 0, stream>>>(d_in[6], 0, hw + HTEXTW, Tn, Dn, flag);
  convT_k<<<dim3(16, 8), blk, 0, stream>>>(d_in[8], 0, hw + HPROJW, Dn, Hn, flag);
  convT_k<<<dim3(16, 16), blk, 0, stream>>>(d_in[22], 0, hw + HHW1, Hn, Hn, flag);
  for (int ii = 0; ii < 2; ++ii) {
    convT_k<<<dim3(16, 16), blk, 0, stream>>>(
        d_in[10], (size_t)ii * 520 * 512, hw + HWE1 + ii * 393216, Hn, Hn, flag);
    convT_k<<<dim3(8, 16), blk, 0, stream>>>(
        d_in[14], (size_t)ii * 520 * 256, hw + HWE1 + ii * 393216 + 262144, Hn, 256, flag);
    convT_k<<<dim3(16, 16), blk, 0, stream>>>(
        d_in[12], (size_t)ii * 512 * 512, hw + HMSGW2 + ii * 262144, Hn, Hn, flag);
    convT_k<<<dim3(16, 8), blk, 0, stream>>>(
        d_in[16], (size_t)ii * 256 * 512, hw + HATTW2 + ii * 131072, 256, Hn, flag);
    convH_k<<<dim3(3072), blk, 0, stream>>>(
        d_in[18], (size_t)ii * 786432, hw + HWIH + ii * 786432, 786432, flag);
    convH_k<<<dim3(3072), blk, 0, stream>>>(
        d_in[19], (size_t)ii * 786432, hw + HWHH + ii * 786432, 786432, flag);
    addv_k<<<dim3(4), blk, 0, stream>>>(bf + FGBIH + ii * 1536, bf + FGBHH + ii * 1536,
                                        bf + FBGRZ + ii * 1024, 1024);
    btype_k<<<dim3(6), blk, 0, stream>>>(
        d_in[11], (size_t)ii * 512, d_in[10], (size_t)ii * 520 * 512 + 512 * 512,
        bf + FBE1 + ii * 2304, 512, 768, flag);
    btype_k<<<dim3(3), blk, 0, stream>>>(
        d_in[15], (size_t)ii * 256, d_in[14], (size_t)ii * 520 * 256 + 512 * 256,
        bf + FBE1 + ii * 2304 + 512, 256, 768, flag);
  }

  // ---- input phase: state(fp16) = relu(proj(X)) ----
  f16* Xc = S;
  const int* gids[3] = {a_ids, b_ids, c_ids};
  const size_t gdst[3] = {0, (size_t)2 * Bn, (size_t)3 * Bn};
  for (int g = 0; g < 3; ++g) {
    gather_k<<<dim3(Bn), dim3(64), 0, stream>>>(gids[g], ent_emb, Xc, flag);
    hgemm_k<EPI_RELU, 5, 0, 2, 0><<<dim3(2 * 128), blk, 0, stream>>>(
        Xc, nullptr, hw + HPROJW, nullptr, bf + FPROJB, nullptr, nullptr,
        nullptr, nullptr, state + gdst[g] * 512, Hn, Dn, Dn, 0, 128, flag);
  }
  hgemm_k<EPI_RELUGATHER, 1, 0, 2, 0><<<dim3(1 * 128), blk, 0, stream>>>(
      text_ab, nullptr, hw + HTEXTW, nullptr, bf + FTEXTB, nullptr, nullptr,
      event_ids, ent_emb, Xc, Dn, Tn, Tn, 0, 128, flag);
  hgemm_k<EPI_RELU, 5, 0, 2, 0><<<dim3(2 * 128), blk, 0, stream>>>(
      Xc, nullptr, hw + HPROJW, nullptr, bf + FPROJB, nullptr, nullptr,
      nullptr, nullptr, state + (size_t)Bn * 512, Hn, Dn, Dn, 0, 128, flag);

  // ---- propagation ----
  for (int ii = 0; ii < 2; ++ii) {
    if (ii > 0)
      relu_h_k<<<dim3(16384), blk, 0, stream>>>((uint4*)state,
                                                (long)4 * Bn * Hn * 2 / 16);
    const f16* Wih = hw + HWIH + (size_t)ii * 786432;
    const f16* Whh = hw + HWHH + (size_t)ii * 786432;
    const f16* Win = Wih + (size_t)1024 * 512;
    const f16* Whn = Whh + (size_t)1024 * 512;
    const float* bgrz = bf + FBGRZ + ii * 1024;
    const float* bihn = bf + FGBIH + ii * 1536 + 1024;
    const float* bhhn = bf + FGBHH + ii * 1536 + 1024;
    for (int p = 0; p < 2; ++p) {
      // E-phase: all 3Bn edges -> P, in 2 chunks of 1.5Bn rows
      for (int c = 0; c < 2; ++c) {
        const int e0 = c * 24576;
        f16* hid = S;  // 1.5Bn x 768 = 36 MB
        hgemm_k<EPI_RELU, 2, 0, 2, 1><<<dim3(3 * 192), blk, 0, stream>>>(
            state, nullptr, hw + HWE1 + ii * 393216, nullptr,
            bf + FBE1 + ii * 2304, nullptr, nullptr, nullptr, nullptr,
            hid, 768, Hn, 512, e0, 192, flag);
        hgemm_k<EPI_NONE, 5, 0, 2, 0><<<dim3(2 * 192), blk, 0, stream>>>(
            hid, nullptr, hw + HMSGW2 + ii * 262144, nullptr, bf + FBE2 + ii * 1024,
            nullptr, nullptr, nullptr, nullptr, P + (size_t)e0 * 512,
            Hn, 512, 768, 0, 192, flag);
        hgemm_k<EPI_SIGMUL, 5, 0, 2, 0><<<dim3(2 * 192), blk, 0, stream>>>(
            hid + 512, nullptr, hw + HATTW2 + ii * 131072, nullptr,
            bf + FBE2 + ii * 1024 + 512, P + (size_t)e0 * 512, nullptr,
            nullptr, nullptr, P + (size_t)e0 * 512, Hn, 256, 768, 0, 192, flag);
      }
      // GRU: chunks r=1..3 (P-fed), each Bn rows
      for (int r = 1; r <= 3; ++r) {
        f16* Pc = P + (size_t)(r - 1) * Bn * 512;
        f16* str = state + (size_t)r * Bn * 512;
        hgemm_k<EPI_SIG, 6, 1, 2, 0><<<dim3(4 * 128), blk, 0, stream>>>(
            Pc, str, Wih, Whh, bgrz, nullptr, nullptr, nullptr, nullptr,
            RZ, 1024, 1024, 512, 0, 128, flag);
        hgemm_k<EPI_NONE, 5, 0, 2, 0><<<dim3(2 * 128), blk, 0, stream>>>(
            str, nullptr, Whn, nullptr, bhhn, nullptr, nullptr, nullptr,
            nullptr, HN, Hn, 512, 512, 0, 128, flag);
        hgemm_k<EPI_GRU, 5, 0, 0, 0><<<dim3(2 * 128), blk, 0, stream>>>(
            Pc, nullptr, Win, nullptr, bihn, RZ, HN, nullptr, nullptr,
            str, Hn, 512, 512, 0, 128, flag);
      }
      // r=0 (A nodes, agg==0)
      hgemm_k<EPI_SIG, 5, 0, 2, 0><<<dim3(4 * 128), blk, 0, stream>>>(
          state, nullptr, Whh, nullptr, bgrz, nullptr, nullptr, nullptr,
          nullptr, RZ, 1024, 512, 512, 0, 128, flag);
      hgemm_k<EPI_NONE, 5, 0, 2, 0><<<dim3(2 * 128), blk, 0, stream>>>(
          state, nullptr, Whn, nullptr, bhhn, nullptr, nullptr, nullptr,
          nullptr, HN, Hn, 512, 512, 0, 128, flag);
      gate0_k<<<dim3(8192), blk, 0, stream>>>(RZ, HN, bihn, state);
    }
  }

  // ---- head ----
  hdiff_k<<<dim3(Bn), dim3(64), 0, stream>>>(state, S);
  hgemm_k<EPI_RELU, 5, 0, 2, 0><<<dim3(2 * 128), blk, 0, stream>>>(
      S, nullptr, hw + HHW1, nullptr, bf + FHB1, nullptr, nullptr, nullptr,
      nullptr, P, Hn, 512, 512, 0, 128, flag);
  head2_k<<<dim3(Bn / 8), blk, 0, stream>>>(P, d_in[24], d_in[25], d_out, flag);
}